// Round 6
// baseline (908.181 us; speedup 1.0000x reference)
//
#include <hip/hip_runtime.h>

#define T_SEQ 512
#define HID 64
#define MB 16             // batch rows per block
#define NTHREADS 1024     // 16 waves, 4/SIMD
// A1 K-layout: [0,64) h1_hi  [64,128) h1_lo  [128,135) x_hi [135,142) x_lo
//              [142,149) x_hi(dup) [149,160) zero
// A2 K-layout: [0,64) h2_hi  [64,128) h2_lo  (GEMM2 h1-ksteps reuse A1 regs)
// Col perm: weight row n = g*64 + u; wave w: u = w*4 + (l15>>2), g = l15&3.
// LOG2E (2*LOG2E for g-gate) folded into W and b at prep time.
#define A1STR 168   // shorts
#define A2STR 136   // shorts

typedef __attribute__((ext_vector_type(8))) short short8;
typedef __attribute__((ext_vector_type(4))) float floatx4;

#define LOG2E 1.4426950408889634f

__device__ __forceinline__ short f2bf(float v) {           // round-half-up (cheap)
  return (short)((__float_as_uint(v) + 0x8000u) >> 16);
}
__device__ __forceinline__ float bf2f(short b) {
  return __uint_as_float(((unsigned)(unsigned short)b) << 16);
}
__device__ __forceinline__ short f2bf_rne(float v) {       // weight prep only
  unsigned u = __float_as_uint(v);
  return (short)((u + 0x7FFFu + ((u >> 16) & 1u)) >> 16);
}
__device__ __forceinline__ float rcp_(float x) { return __builtin_amdgcn_rcpf(x); }
// activations on PRE-SCALED gates: ap = LOG2E*a (i,f,o), yp = 2*LOG2E*y (g)
__device__ __forceinline__ float sigm_p(float ap) {
  return rcp_(1.f + __builtin_amdgcn_exp2f(-ap));
}
__device__ __forceinline__ float tanh_p(float yp) {
  return 1.f - 2.f * rcp_(__builtin_amdgcn_exp2f(yp) + 1.f);
}
__device__ __forceinline__ float tanh_c(float c) {         // unscaled c
  return tanh_p((2.f * LOG2E) * c);
}

// B1[k][n], pre-scaled by wsc (gate-dependent), bf16 hi/lo bits
__device__ __forceinline__ short w1elem(int k, int n, float wsc,
                                        const float* __restrict__ Wih0,
                                        const float* __restrict__ Whh0) {
  float v; bool lo = false;
  if      (k < 64)  { v = Whh0[n*64 + k]; }
  else if (k < 128) { v = Whh0[n*64 + (k-64)]; }
  else if (k < 192) { v = Whh0[n*64 + (k-128)]; lo = true; }
  else if (k < 199) { v = Wih0[n*7 + (k-192)]; }
  else if (k < 206) { v = Wih0[n*7 + (k-199)]; }
  else if (k < 213) { v = Wih0[n*7 + (k-206)]; lo = true; }
  else return (short)0;
  v *= wsc;
  short h = f2bf_rne(v);
  if (!lo) return h;
  return f2bf_rne(v - bf2f(h));
}
__device__ __forceinline__ short w2elem(int k, int n, float wsc,
                                        const float* __restrict__ Wih1,
                                        const float* __restrict__ Whh1) {
  float v; bool lo = false;
  if      (k < 64)  { v = Wih1[n*64 + k]; }
  else if (k < 128) { v = Wih1[n*64 + (k-64)]; }
  else if (k < 192) { v = Wih1[n*64 + (k-128)]; lo = true; }
  else if (k < 256) { v = Whh1[n*64 + (k-192)]; }
  else if (k < 320) { v = Whh1[n*64 + (k-256)]; }
  else              { v = Whh1[n*64 + (k-320)]; lo = true; }
  v *= wsc;
  short h = f2bf_rne(v);
  if (!lo) return h;
  return f2bf_rne(v - bf2f(h));
}

#define MFMA(A, B, C) __builtin_amdgcn_mfma_f32_16x16x32_bf16((A), (B), (C), 0, 0, 0)

// 4x4 transpose across lane bits 0-1
#define XPOSE4(a0, a1, a2, a3, gsel)                                 \
  {                                                                  \
    float s_;                                                        \
    s_ = __shfl_xor((gsel & 1) ? a0 : a1, 1);                        \
    if (gsel & 1) a0 = s_; else a1 = s_;                             \
    s_ = __shfl_xor((gsel & 1) ? a2 : a3, 1);                        \
    if (gsel & 1) a2 = s_; else a3 = s_;                             \
    s_ = __shfl_xor((gsel & 2) ? a0 : a2, 2);                        \
    if (gsel & 2) a0 = s_; else a2 = s_;                             \
    s_ = __shfl_xor((gsel & 2) ? a1 : a3, 2);                        \
    if (gsel & 2) a1 = s_; else a3 = s_;                             \
  }

__global__ __launch_bounds__(NTHREADS, 4) void lstm_fused(
    const float* __restrict__ x,
    const float* __restrict__ Wih0, const float* __restrict__ Whh0,
    const float* __restrict__ bih0, const float* __restrict__ bhh0,
    const float* __restrict__ Wih1, const float* __restrict__ Whh1,
    const float* __restrict__ bih1, const float* __restrict__ bhh1,
    const float* __restrict__ Wfc,  const float* __restrict__ bfc,
    float* __restrict__ out)
{
  __shared__ __align__(16) short A1[2][MB][A1STR];
  __shared__ __align__(16) short A2[2][MB][A2STR];
  __shared__ float h2f[MB][HID + 4];

  const int tid  = threadIdx.x;
  const int lane = tid & 63;
  const int wave = tid >> 6;
  const int l15  = lane & 15;
  const int quad = lane >> 4;
  const int quad8= quad * 8;
  const int g4   = l15 & 3;
  const int b0   = blockIdx.x * MB;
  const int row  = quad * 4 + g4;           // batch row owned post-transpose
  const int u0   = wave * 4 + (l15 >> 2);   // unit owned
  const int n    = g4 * 64 + u0;            // permuted weight row
  const float wsc = (g4 == 2) ? 2.f * LOG2E : LOG2E;  // g-gate gets 2*LOG2E

  // ---- init: zero both A-staging buffers ----
  for (int i = tid; i < 2*MB*A1STR/2; i += NTHREADS) ((unsigned*)A1)[i] = 0u;
  for (int i = tid; i < 2*MB*A2STR/2; i += NTHREADS) ((unsigned*)A2)[i] = 0u;

  const float bc1 = (bih0[n] + bhh0[n]) * wsc;
  const float bc2 = (bih1[n] + bhh1[n]) * wsc;

  // ---- stage x(0) into A1[0]; xcur = x(1) ----
  const int xb = tid / 7, xd = tid - xb * 7;
  const float* xbase = x + ((size_t)(b0 + (xb & 15)) * T_SEQ) * 7 + xd;
  float xcur = 0.f;
  if (tid < 112) {
    float xv = xbase[0];
    short xh = f2bf(xv); short xl = f2bf(xv - bf2f(xh));
    A1[0][xb][128 + xd] = xh; A1[0][xb][135 + xd] = xl; A1[0][xb][142 + xd] = xh;
    xcur = xbase[7];
  }

  // ---- weight B-fragments in registers ----
  short8 B1f[7];
  short8 B2f[12];
  #pragma unroll
  for (int ks = 0; ks < 7; ++ks) {
    short8 f;
    #pragma unroll
    for (int jj = 0; jj < 8; ++jj) f[jj] = w1elem(ks*32 + quad8 + jj, n, wsc, Wih0, Whh0);
    B1f[ks] = f;
  }
  #pragma unroll
  for (int ks = 0; ks < 12; ++ks) {
    short8 f;
    #pragma unroll
    for (int jj = 0; jj < 8; ++jj) f[jj] = w2elem(ks*32 + quad8 + jj, n, wsc, Wih1, Whh1);
    B2f[ks] = f;
  }
  __syncthreads();

  float c1 = 0.f, c2 = 0.f;

// One full timestep: GEMM1(it)+GEMM2(it-1)+elementwise, buffers CUR->NXT.
// x: stores x(it+1) (=xcur) into NXT early, then loads x(min(it+2,511)).
#define STEP_X(NXT, XT)                                                      \
    if (tid < 112) {                                                         \
      short xh = f2bf(xcur); short xl = f2bf(xcur - bf2f(xh));               \
      A1[NXT][xb][128 + xd] = xh; A1[NXT][xb][135 + xd] = xl;                \
      A1[NXT][xb][142 + xd] = xh;                                            \
      xcur = xbase[7 * (XT)];                                                \
    }

#define STEP_FULL(CUR, NXT, IT)                                              \
  {                                                                          \
    int xt_ = (IT) + 2; if (xt_ > T_SEQ - 1) xt_ = T_SEQ - 1;                \
    STEP_X(NXT, xt_)                                                         \
    short8 af0 = *(const short8*)&A1[CUR][l15][      quad8];                 \
    short8 af1 = *(const short8*)&A1[CUR][l15][ 32 + quad8];                 \
    short8 af2 = *(const short8*)&A1[CUR][l15][ 64 + quad8];                 \
    short8 af3 = *(const short8*)&A1[CUR][l15][ 96 + quad8];                 \
    short8 af6 = *(const short8*)&A1[CUR][l15][128 + quad8];                 \
    short8 h20 = *(const short8*)&A2[CUR][l15][      quad8];                 \
    short8 h21 = *(const short8*)&A2[CUR][l15][ 32 + quad8];                 \
    short8 h22 = *(const short8*)&A2[CUR][l15][ 64 + quad8];                 \
    short8 h23 = *(const short8*)&A2[CUR][l15][ 96 + quad8];                 \
    floatx4 p1 = {bc1, bc1, bc1, bc1};                                       \
    p1 = MFMA(af0, B1f[0], p1);                                              \
    p1 = MFMA(af1, B1f[1], p1);                                              \
    p1 = MFMA(af2, B1f[2], p1);                                              \
    p1 = MFMA(af3, B1f[3], p1);                                              \
    p1 = MFMA(af0, B1f[4], p1);                                              \
    p1 = MFMA(af1, B1f[5], p1);                                              \
    p1 = MFMA(af6, B1f[6], p1);                                              \
    floatx4 p2 = {bc2, bc2, bc2, bc2};                                       \
    p2 = MFMA(af0, B2f[0],  p2);                                             \
    p2 = MFMA(af1, B2f[1],  p2);                                             \
    p2 = MFMA(af2, B2f[2],  p2);                                             \
    p2 = MFMA(af3, B2f[3],  p2);                                             \
    p2 = MFMA(af0, B2f[4],  p2);                                             \
    p2 = MFMA(af1, B2f[5],  p2);                                             \
    p2 = MFMA(h20, B2f[6],  p2);                                             \
    p2 = MFMA(h21, B2f[7],  p2);                                             \
    p2 = MFMA(h22, B2f[8],  p2);                                             \
    p2 = MFMA(h23, B2f[9],  p2);                                             \
    p2 = MFMA(h20, B2f[10], p2);                                             \
    p2 = MFMA(h21, B2f[11], p2);                                             \
    {                                                                        \
      float a0 = p1[0], a1 = p1[1], a2 = p1[2], a3 = p1[3];                  \
      XPOSE4(a0, a1, a2, a3, g4);                                            \
      float iv = sigm_p(a0), fv = sigm_p(a1), gv = tanh_p(a2), ov = sigm_p(a3);\
      c1 = fv * c1 + iv * gv;                                                \
      float h = ov * tanh_c(c1);                                             \
      short hh = f2bf(h); short hl = f2bf(h - bf2f(hh));                     \
      A1[NXT][row][u0] = hh; A1[NXT][row][64 + u0] = hl;                     \
    }                                                                        \
    {                                                                        \
      float a0 = p2[0], a1 = p2[1], a2 = p2[2], a3 = p2[3];                  \
      XPOSE4(a0, a1, a2, a3, g4);                                            \
      float iv = sigm_p(a0), fv = sigm_p(a1), gv = tanh_p(a2), ov = sigm_p(a3);\
      c2 = fv * c2 + iv * gv;                                                \
      float h = ov * tanh_c(c2);                                             \
      short hh = f2bf(h); short hl = f2bf(h - bf2f(hh));                     \
      A2[NXT][row][u0] = hh; A2[NXT][row][64 + u0] = hl;                     \
    }                                                                        \
    __syncthreads();                                                         \
  }

  // ---- it = 0 (prologue: GEMM1 + ew1 only; A2[1] keeps its zeros) ----
  {
    STEP_X(1, 2)
    short8 af0 = *(const short8*)&A1[0][l15][      quad8];
    short8 af1 = *(const short8*)&A1[0][l15][ 32 + quad8];
    short8 af2 = *(const short8*)&A1[0][l15][ 64 + quad8];
    short8 af3 = *(const short8*)&A1[0][l15][ 96 + quad8];
    short8 af6 = *(const short8*)&A1[0][l15][128 + quad8];
    floatx4 p1 = {bc1, bc1, bc1, bc1};
    p1 = MFMA(af0, B1f[0], p1);
    p1 = MFMA(af1, B1f[1], p1);
    p1 = MFMA(af2, B1f[2], p1);
    p1 = MFMA(af3, B1f[3], p1);
    p1 = MFMA(af0, B1f[4], p1);
    p1 = MFMA(af1, B1f[5], p1);
    p1 = MFMA(af6, B1f[6], p1);
    float a0 = p1[0], a1 = p1[1], a2 = p1[2], a3 = p1[3];
    XPOSE4(a0, a1, a2, a3, g4);
    float iv = sigm_p(a0), fv = sigm_p(a1), gv = tanh_p(a2), ov = sigm_p(a3);
    c1 = fv * c1 + iv * gv;
    float h = ov * tanh_c(c1);
    short hh = f2bf(h); short hl = f2bf(h - bf2f(hh));
    A1[1][row][u0] = hh; A1[1][row][64 + u0] = hl;
    __syncthreads();
  }

  // ---- main: it = 1..510, two steps per trip ----
  #pragma unroll 1
  for (int k = 0; k < 255; ++k) {
    STEP_FULL(1, 0, 2*k + 1)
    STEP_FULL(0, 1, 2*k + 2)
  }
  // ---- it = 511 ----
  STEP_FULL(1, 0, 511)

  // ---- it = 512 (epilogue: GEMM2 + ew2 only, write h2 final) ----
  {
    short8 af0 = *(const short8*)&A1[0][l15][      quad8];
    short8 af1 = *(const short8*)&A1[0][l15][ 32 + quad8];
    short8 af2 = *(const short8*)&A1[0][l15][ 64 + quad8];
    short8 af3 = *(const short8*)&A1[0][l15][ 96 + quad8];
    short8 h20 = *(const short8*)&A2[0][l15][      quad8];
    short8 h21 = *(const short8*)&A2[0][l15][ 32 + quad8];
    short8 h22 = *(const short8*)&A2[0][l15][ 64 + quad8];
    short8 h23 = *(const short8*)&A2[0][l15][ 96 + quad8];
    floatx4 p2 = {bc2, bc2, bc2, bc2};
    p2 = MFMA(af0, B2f[0],  p2);
    p2 = MFMA(af1, B2f[1],  p2);
    p2 = MFMA(af2, B2f[2],  p2);
    p2 = MFMA(af3, B2f[3],  p2);
    p2 = MFMA(af0, B2f[4],  p2);
    p2 = MFMA(af1, B2f[5],  p2);
    p2 = MFMA(h20, B2f[6],  p2);
    p2 = MFMA(h21, B2f[7],  p2);
    p2 = MFMA(h22, B2f[8],  p2);
    p2 = MFMA(h23, B2f[9],  p2);
    p2 = MFMA(h20, B2f[10], p2);
    p2 = MFMA(h21, B2f[11], p2);
    float a0 = p2[0], a1 = p2[1], a2 = p2[2], a3 = p2[3];
    XPOSE4(a0, a1, a2, a3, g4);
    float iv = sigm_p(a0), fv = sigm_p(a1), gv = tanh_p(a2), ov = sigm_p(a3);
    c2 = fv * c2 + iv * gv;
    h2f[row][u0] = ov * tanh_c(c2);
    __syncthreads();
  }

  // ---- final FC ----
  if (tid < MB * 4) {
    int bbf = tid >> 2, o = tid & 3;
    float acc = bfc[o];
    #pragma unroll 8
    for (int kk = 0; kk < HID; ++kk) acc += h2f[bbf][kk] * Wfc[o*HID + kk];
    out[(size_t)(b0 + bbf) * 4 + o] = acc;
  }
}

extern "C" void kernel_launch(void* const* d_in, const int* in_sizes, int n_in,
                              void* d_out, int out_size, void* d_ws, size_t ws_size,
                              hipStream_t stream) {
  const float* x    = (const float*)d_in[0];
  const float* Wih0 = (const float*)d_in[1];
  const float* Whh0 = (const float*)d_in[2];
  const float* bih0 = (const float*)d_in[3];
  const float* bhh0 = (const float*)d_in[4];
  const float* Wih1 = (const float*)d_in[5];
  const float* Whh1 = (const float*)d_in[6];
  const float* bih1 = (const float*)d_in[7];
  const float* bhh1 = (const float*)d_in[8];
  const float* Wfc  = (const float*)d_in[9];
  const float* bfc  = (const float*)d_in[10];
  (void)d_ws; (void)ws_size; (void)n_in; (void)out_size;

  const int B = in_sizes[0] / (T_SEQ * 7);   // 4096
  dim3 grid(B / MB);
  lstm_fused<<<grid, NTHREADS, 0, stream>>>(x, Wih0, Whh0, bih0, bhh0,
                                            Wih1, Whh1, bih1, bhh1, Wfc, bfc,
                                            (float*)d_out);
}

// Round 7
// 722.023 us; speedup vs baseline: 1.2578x; 1.2578x over previous
//
#include <hip/hip_runtime.h>

#define T_SEQ 512
#define HID 64
#define MB 16             // batch rows per block
#define NTHREADS 1024     // 16 waves, 4/SIMD
// OPERAND-FLIPPED MFMA: A = weights (regs), B = h (LDS). D[gate-unit][batch]:
// lane (quad,l15) holds gates i,f,g,o (regs 0..3) of unit wave*4+quad, batch l15.
// A1 K-layout: [0,64) h1_hi  [64,128) h1_lo  [128,135) x_hi [135,142) x_lo
//              [142,149) x_hi(dup) [149,160) zero
// A2 K-layout: [0,64) h2_hi  [64,128) h2_lo  (GEMM2 h1-ksteps reuse A1 regs)
// LOG2E (2*LOG2E for g-gate) folded into W and b at prep time.
#define A1STR 168   // shorts
#define A2STR 136   // shorts

typedef __attribute__((ext_vector_type(8))) short short8;
typedef __attribute__((ext_vector_type(4))) float floatx4;

#define LOG2E 1.4426950408889634f

__device__ __forceinline__ short f2bf(float v) {           // round-half-up (cheap)
  return (short)((__float_as_uint(v) + 0x8000u) >> 16);
}
__device__ __forceinline__ float bf2f(short b) {
  return __uint_as_float(((unsigned)(unsigned short)b) << 16);
}
__device__ __forceinline__ short f2bf_rne(float v) {       // weight prep only
  unsigned u = __float_as_uint(v);
  return (short)((u + 0x7FFFu + ((u >> 16) & 1u)) >> 16);
}
__device__ __forceinline__ float rcp_(float x) { return __builtin_amdgcn_rcpf(x); }
// activations on PRE-SCALED gates: ap = LOG2E*a (i,f,o), yp = 2*LOG2E*y (g)
__device__ __forceinline__ float sigm_p(float ap) {
  return rcp_(1.f + __builtin_amdgcn_exp2f(-ap));
}
__device__ __forceinline__ float tanh_p(float yp) {
  return 1.f - 2.f * rcp_(__builtin_amdgcn_exp2f(yp) + 1.f);
}
__device__ __forceinline__ float tanh_c(float c) {         // unscaled c
  return tanh_p((2.f * LOG2E) * c);
}

// Weight element (bf16 bits) at [row n][k-slot k], pre-scaled by wsc
__device__ __forceinline__ short w1elem(int k, int n, float wsc,
                                        const float* __restrict__ Wih0,
                                        const float* __restrict__ Whh0) {
  float v; bool lo = false;
  if      (k < 64)  { v = Whh0[n*64 + k]; }
  else if (k < 128) { v = Whh0[n*64 + (k-64)]; }
  else if (k < 192) { v = Whh0[n*64 + (k-128)]; lo = true; }
  else if (k < 199) { v = Wih0[n*7 + (k-192)]; }
  else if (k < 206) { v = Wih0[n*7 + (k-199)]; }
  else if (k < 213) { v = Wih0[n*7 + (k-206)]; lo = true; }
  else return (short)0;
  v *= wsc;
  short h = f2bf_rne(v);
  if (!lo) return h;
  return f2bf_rne(v - bf2f(h));
}
__device__ __forceinline__ short w2elem(int k, int n, float wsc,
                                        const float* __restrict__ Wih1,
                                        const float* __restrict__ Whh1) {
  float v; bool lo = false;
  if      (k < 64)  { v = Wih1[n*64 + k]; }
  else if (k < 128) { v = Wih1[n*64 + (k-64)]; }
  else if (k < 192) { v = Wih1[n*64 + (k-128)]; lo = true; }
  else if (k < 256) { v = Whh1[n*64 + (k-192)]; }
  else if (k < 320) { v = Whh1[n*64 + (k-256)]; }
  else              { v = Whh1[n*64 + (k-320)]; lo = true; }
  v *= wsc;
  short h = f2bf_rne(v);
  if (!lo) return h;
  return f2bf_rne(v - bf2f(h));
}

// A = weights (first arg), B = h (second arg)
#define MFMA(A, B, C) __builtin_amdgcn_mfma_f32_16x16x32_bf16((A), (B), (C), 0, 0, 0)

__global__ __launch_bounds__(NTHREADS, 4) void lstm_fused(
    const float* __restrict__ x,
    const float* __restrict__ Wih0, const float* __restrict__ Whh0,
    const float* __restrict__ bih0, const float* __restrict__ bhh0,
    const float* __restrict__ Wih1, const float* __restrict__ Whh1,
    const float* __restrict__ bih1, const float* __restrict__ bhh1,
    const float* __restrict__ Wfc,  const float* __restrict__ bfc,
    float* __restrict__ out)
{
  __shared__ __align__(16) short A1[2][MB][A1STR];
  __shared__ __align__(16) short A2[2][MB][A2STR];
  __shared__ float h2f[MB][HID + 4];

  const int tid  = threadIdx.x;
  const int lane = tid & 63;
  const int wave = tid >> 6;
  const int l15  = lane & 15;          // = batch column (D n-index)
  const int quad = lane >> 4;
  const int quad8= quad * 8;
  const int g4   = l15 & 3;            // gate of this lane's A-frag rows
  const int b0   = blockIdx.x * MB;
  const int un   = wave * 4 + quad;    // unit owned post-MFMA (D m-rows quad*4+g)
  const int n    = g4 * 64 + (wave * 4 + (l15 >> 2));  // A-frag weight row
  const float wsc = (g4 == 2) ? 2.f * LOG2E : LOG2E;

  // ---- init: zero both A-staging buffers ----
  for (int i = tid; i < 2*MB*A1STR/2; i += NTHREADS) ((unsigned*)A1)[i] = 0u;
  for (int i = tid; i < 2*MB*A2STR/2; i += NTHREADS) ((unsigned*)A2)[i] = 0u;

  // ---- per-thread bias vectors for unit `un` (gate order i,f,g,o in regs) ----
  floatx4 bi1v, bi2v;
  #pragma unroll
  for (int g = 0; g < 4; ++g) {
    float ws = (g == 2) ? 2.f * LOG2E : LOG2E;
    bi1v[g] = (bih0[g*64 + un] + bhh0[g*64 + un]) * ws;
    bi2v[g] = (bih1[g*64 + un] + bhh1[g*64 + un]) * ws;
  }

  // ---- stage x(0) into A1[0]; xcur = x(1) ----
  const int xb = tid / 7, xd = tid - xb * 7;
  const float* xbase = x + ((size_t)(b0 + (xb & 15)) * T_SEQ) * 7 + xd;
  float xcur = 0.f;
  if (tid < 112) {
    float xv = xbase[0];
    short xh = f2bf(xv); short xl = f2bf(xv - bf2f(xh));
    A1[0][xb][128 + xd] = xh; A1[0][xb][135 + xd] = xl; A1[0][xb][142 + xd] = xh;
    xcur = xbase[7];
  }

  // ---- weight A-fragments in registers (same layout math as before) ----
  short8 B1f[7];
  short8 B2f[12];
  #pragma unroll
  for (int ks = 0; ks < 7; ++ks) {
    short8 f;
    #pragma unroll
    for (int jj = 0; jj < 8; ++jj) f[jj] = w1elem(ks*32 + quad8 + jj, n, wsc, Wih0, Whh0);
    B1f[ks] = f;
  }
  #pragma unroll
  for (int ks = 0; ks < 12; ++ks) {
    short8 f;
    #pragma unroll
    for (int jj = 0; jj < 8; ++jj) f[jj] = w2elem(ks*32 + quad8 + jj, n, wsc, Wih1, Whh1);
    B2f[ks] = f;
  }
  __syncthreads();

  float c1 = 0.f, c2 = 0.f;

#define STEP_X(NXT, XT)                                                      \
    if (tid < 112) {                                                         \
      short xh = f2bf(xcur); short xl = f2bf(xcur - bf2f(xh));               \
      A1[NXT][xb][128 + xd] = xh; A1[NXT][xb][135 + xd] = xl;                \
      A1[NXT][xb][142 + xd] = xh;                                            \
      xcur = xbase[7 * (XT)];                                                \
    }

#define STEP_FULL(CUR, NXT, IT)                                              \
  {                                                                          \
    int xt_ = (IT) + 2; if (xt_ > T_SEQ - 1) xt_ = T_SEQ - 1;                \
    STEP_X(NXT, xt_)                                                         \
    short8 hf0 = *(const short8*)&A1[CUR][l15][      quad8];                 \
    short8 hf1 = *(const short8*)&A1[CUR][l15][ 32 + quad8];                 \
    short8 hf2 = *(const short8*)&A1[CUR][l15][ 64 + quad8];                 \
    short8 hf3 = *(const short8*)&A1[CUR][l15][ 96 + quad8];                 \
    short8 hf6 = *(const short8*)&A1[CUR][l15][128 + quad8];                 \
    short8 h20 = *(const short8*)&A2[CUR][l15][      quad8];                 \
    short8 h21 = *(const short8*)&A2[CUR][l15][ 32 + quad8];                 \
    short8 h22 = *(const short8*)&A2[CUR][l15][ 64 + quad8];                 \
    short8 h23 = *(const short8*)&A2[CUR][l15][ 96 + quad8];                 \
    floatx4 p1 = bi1v;                                                       \
    p1 = MFMA(B1f[0], hf0, p1);                                              \
    p1 = MFMA(B1f[1], hf1, p1);                                              \
    p1 = MFMA(B1f[2], hf2, p1);                                              \
    p1 = MFMA(B1f[3], hf3, p1);                                              \
    p1 = MFMA(B1f[4], hf0, p1);                                              \
    p1 = MFMA(B1f[5], hf1, p1);                                              \
    p1 = MFMA(B1f[6], hf6, p1);                                              \
    floatx4 p2 = bi2v;                                                       \
    p2 = MFMA(B2f[0],  hf0, p2);                                             \
    p2 = MFMA(B2f[1],  hf1, p2);                                             \
    p2 = MFMA(B2f[2],  hf2, p2);                                             \
    p2 = MFMA(B2f[3],  hf3, p2);                                             \
    p2 = MFMA(B2f[4],  hf0, p2);                                             \
    p2 = MFMA(B2f[5],  hf1, p2);                                             \
    p2 = MFMA(B2f[6],  h20, p2);                                             \
    p2 = MFMA(B2f[7],  h21, p2);                                             \
    p2 = MFMA(B2f[8],  h22, p2);                                             \
    p2 = MFMA(B2f[9],  h23, p2);                                             \
    p2 = MFMA(B2f[10], h20, p2);                                             \
    p2 = MFMA(B2f[11], h21, p2);                                             \
    {                                                                        \
      float iv = sigm_p(p1[0]), fv = sigm_p(p1[1]);                          \
      float gv = tanh_p(p1[2]), ov = sigm_p(p1[3]);                          \
      c1 = fv * c1 + iv * gv;                                                \
      float h = ov * tanh_c(c1);                                             \
      short hh = f2bf(h); short hl = f2bf(h - bf2f(hh));                     \
      A1[NXT][l15][un] = hh; A1[NXT][l15][64 + un] = hl;                     \
    }                                                                        \
    {                                                                        \
      float iv = sigm_p(p2[0]), fv = sigm_p(p2[1]);                          \
      float gv = tanh_p(p2[2]), ov = sigm_p(p2[3]);                          \
      c2 = fv * c2 + iv * gv;                                                \
      float h = ov * tanh_c(c2);                                             \
      short hh = f2bf(h); short hl = f2bf(h - bf2f(hh));                     \
      A2[NXT][l15][un] = hh; A2[NXT][l15][64 + un] = hl;                     \
    }                                                                        \
    __syncthreads();                                                         \
  }

  // ---- it = 0 (prologue: GEMM1 + ew1 only; A2[1] keeps its zeros) ----
  {
    STEP_X(1, 2)
    short8 hf0 = *(const short8*)&A1[0][l15][      quad8];
    short8 hf1 = *(const short8*)&A1[0][l15][ 32 + quad8];
    short8 hf2 = *(const short8*)&A1[0][l15][ 64 + quad8];
    short8 hf3 = *(const short8*)&A1[0][l15][ 96 + quad8];
    short8 hf6 = *(const short8*)&A1[0][l15][128 + quad8];
    floatx4 p1 = bi1v;
    p1 = MFMA(B1f[0], hf0, p1);
    p1 = MFMA(B1f[1], hf1, p1);
    p1 = MFMA(B1f[2], hf2, p1);
    p1 = MFMA(B1f[3], hf3, p1);
    p1 = MFMA(B1f[4], hf0, p1);
    p1 = MFMA(B1f[5], hf1, p1);
    p1 = MFMA(B1f[6], hf6, p1);
    float iv = sigm_p(p1[0]), fv = sigm_p(p1[1]);
    float gv = tanh_p(p1[2]), ov = sigm_p(p1[3]);
    c1 = fv * c1 + iv * gv;
    float h = ov * tanh_c(c1);
    short hh = f2bf(h); short hl = f2bf(h - bf2f(hh));
    A1[1][l15][un] = hh; A1[1][l15][64 + un] = hl;
    __syncthreads();
  }

  // ---- main: it = 1..510, two steps per trip ----
  #pragma unroll 1
  for (int k = 0; k < 255; ++k) {
    STEP_FULL(1, 0, 2*k + 1)
    STEP_FULL(0, 1, 2*k + 2)
  }
  // ---- it = 511 ----
  STEP_FULL(1, 0, 511)

  // ---- it = 512 (epilogue: GEMM2 + ew2 only, write h2 final) ----
  {
    short8 hf0 = *(const short8*)&A1[0][l15][      quad8];
    short8 hf1 = *(const short8*)&A1[0][l15][ 32 + quad8];
    short8 hf2 = *(const short8*)&A1[0][l15][ 64 + quad8];
    short8 hf3 = *(const short8*)&A1[0][l15][ 96 + quad8];
    short8 h20 = *(const short8*)&A2[0][l15][      quad8];
    short8 h21 = *(const short8*)&A2[0][l15][ 32 + quad8];
    short8 h22 = *(const short8*)&A2[0][l15][ 64 + quad8];
    short8 h23 = *(const short8*)&A2[0][l15][ 96 + quad8];
    floatx4 p2 = bi2v;
    p2 = MFMA(B2f[0],  hf0, p2);
    p2 = MFMA(B2f[1],  hf1, p2);
    p2 = MFMA(B2f[2],  hf2, p2);
    p2 = MFMA(B2f[3],  hf3, p2);
    p2 = MFMA(B2f[4],  hf0, p2);
    p2 = MFMA(B2f[5],  hf1, p2);
    p2 = MFMA(B2f[6],  h20, p2);
    p2 = MFMA(B2f[7],  h21, p2);
    p2 = MFMA(B2f[8],  h22, p2);
    p2 = MFMA(B2f[9],  h23, p2);
    p2 = MFMA(B2f[10], h20, p2);
    p2 = MFMA(B2f[11], h21, p2);
    float iv = sigm_p(p2[0]), fv = sigm_p(p2[1]);
    float gv = tanh_p(p2[2]), ov = sigm_p(p2[3]);
    c2 = fv * c2 + iv * gv;
    h2f[l15][un] = ov * tanh_c(c2);
    __syncthreads();
  }

  // ---- final FC ----
  if (tid < MB * 4) {
    int bbf = tid >> 2, o = tid & 3;
    float acc = bfc[o];
    #pragma unroll 8
    for (int kk = 0; kk < HID; ++kk) acc += h2f[bbf][kk] * Wfc[o*HID + kk];
    out[(size_t)(b0 + bbf) * 4 + o] = acc;
  }
}

extern "C" void kernel_launch(void* const* d_in, const int* in_sizes, int n_in,
                              void* d_out, int out_size, void* d_ws, size_t ws_size,
                              hipStream_t stream) {
  const float* x    = (const float*)d_in[0];
  const float* Wih0 = (const float*)d_in[1];
  const float* Whh0 = (const float*)d_in[2];
  const float* bih0 = (const float*)d_in[3];
  const float* bhh0 = (const float*)d_in[4];
  const float* Wih1 = (const float*)d_in[5];
  const float* Whh1 = (const float*)d_in[6];
  const float* bih1 = (const float*)d_in[7];
  const float* bhh1 = (const float*)d_in[8];
  const float* Wfc  = (const float*)d_in[9];
  const float* bfc  = (const float*)d_in[10];
  (void)d_ws; (void)ws_size; (void)n_in; (void)out_size;

  const int B = in_sizes[0] / (T_SEQ * 7);   // 4096
  dim3 grid(B / MB);
  lstm_fused<<<grid, NTHREADS, 0, stream>>>(x, Wih0, Whh0, bih0, bhh0,
                                            Wih1, Whh1, bih1, bhh1, Wfc, bfc,
                                            (float*)d_out);
}

// Round 8
// 611.624 us; speedup vs baseline: 1.4849x; 1.1805x over previous
//
#include <hip/hip_runtime.h>

#define T_SEQ 512
#define HID 64
#define MB 16             // batch rows per block
#define NTHREADS 1024     // 16 waves, 4/SIMD
// OPERAND-FLIPPED MFMA: A = weights (regs), B = h (LDS). D[gate-unit][batch]:
// lane (quad,l15) holds gates i,f,g,o (regs 0..3) of unit wave*4+quad, batch l15.
// INTERLEAVED hi/lo layout (W_lo terms dropped — error budget allows):
// A1 row: short 2u = h1_hi[u], 2u+1 = h1_lo[u]  (k in [0,128), 4 ksteps)
//         short 128+2d = x_hi[d], 129+2d = x_lo[d], d<7; [142,160) zero (kstep 4)
// A2 row: short 2u = h2_hi[u], 2u+1 = h2_lo[u]  (k in [0,128), 4 ksteps)
// W slot for k = W_hi[n][k>>1] (same W pairs hi and lo h-slots).
// h-store = ONE packed b32 (hi|lo<<16): banks (20*l15+4w+quad) cover all 32,
// 2 lanes/bank -> conflict-free.
#define A1STR 168   // shorts; 84 dw == 4 mod 8: max row-base bank spread @16B align
#define A2STR 136   // shorts; 68 dw == 4 mod 8

typedef __attribute__((ext_vector_type(8))) short short8;
typedef __attribute__((ext_vector_type(4))) float floatx4;

#define LOG2E 1.4426950408889634f

__device__ __forceinline__ short f2bf(float v) {           // round-half-up (cheap)
  return (short)((__float_as_uint(v) + 0x8000u) >> 16);
}
__device__ __forceinline__ float bf2f(short b) {
  return __uint_as_float(((unsigned)(unsigned short)b) << 16);
}
__device__ __forceinline__ short f2bf_rne(float v) {       // weight prep only
  unsigned u = __float_as_uint(v);
  return (short)((u + 0x7FFFu + ((u >> 16) & 1u)) >> 16);
}
__device__ __forceinline__ float rcp_(float x) { return __builtin_amdgcn_rcpf(x); }
// activations on PRE-SCALED gates: ap = LOG2E*a (i,f,o), yp = 2*LOG2E*y (g)
__device__ __forceinline__ float sigm_p(float ap) {
  return rcp_(1.f + __builtin_amdgcn_exp2f(-ap));
}
__device__ __forceinline__ float tanh_p(float yp) {
  return 1.f - 2.f * rcp_(__builtin_amdgcn_exp2f(yp) + 1.f);
}
__device__ __forceinline__ float tanh_c(float c) {         // unscaled c
  return tanh_p((2.f * LOG2E) * c);
}

// W1 slot k (interleaved map): k<128 -> Whh0_hi[n][k>>1]; 128..141 -> Wih0_hi; else 0
__device__ __forceinline__ short w1elem(int k, int n, float wsc,
                                        const float* __restrict__ Wih0,
                                        const float* __restrict__ Whh0) {
  float v;
  if      (k < 128) { v = Whh0[n*64 + (k >> 1)]; }
  else if (k < 142) { v = Wih0[n*7 + ((k - 128) >> 1)]; }
  else return (short)0;
  return f2bf_rne(v * wsc);
}
// W2 slot k: k<128 -> Wih1_hi[n][k>>1] (pairs h1); 128..255 -> Whh1_hi (pairs h2)
__device__ __forceinline__ short w2elem(int k, int n, float wsc,
                                        const float* __restrict__ Wih1,
                                        const float* __restrict__ Whh1) {
  float v;
  if (k < 128) { v = Wih1[n*64 + (k >> 1)]; }
  else         { v = Whh1[n*64 + ((k - 128) >> 1)]; }
  return f2bf_rne(v * wsc);
}

// A = weights (first arg), B = h (second arg)
#define MFMA(A, B, C) __builtin_amdgcn_mfma_f32_16x16x32_bf16((A), (B), (C), 0, 0, 0)

__global__ __launch_bounds__(NTHREADS, 4) void lstm_fused(
    const float* __restrict__ x,
    const float* __restrict__ Wih0, const float* __restrict__ Whh0,
    const float* __restrict__ bih0, const float* __restrict__ bhh0,
    const float* __restrict__ Wih1, const float* __restrict__ Whh1,
    const float* __restrict__ bih1, const float* __restrict__ bhh1,
    const float* __restrict__ Wfc,  const float* __restrict__ bfc,
    float* __restrict__ out)
{
  __shared__ __align__(16) short A1[2][MB][A1STR];
  __shared__ __align__(16) short A2[2][MB][A2STR];
  __shared__ float h2f[MB][HID + 4];

  const int tid  = threadIdx.x;
  const int lane = tid & 63;
  const int wave = tid >> 6;
  const int l15  = lane & 15;          // batch column (D n-index)
  const int quad = lane >> 4;
  const int quad8= quad * 8;
  const int g4   = l15 & 3;            // gate of this lane's A-frag rows
  const int b0   = blockIdx.x * MB;
  const int un   = wave * 4 + quad;    // unit owned post-MFMA
  const int n    = g4 * 64 + (wave * 4 + (l15 >> 2));  // A-frag weight row
  const float wsc = (g4 == 2) ? 2.f * LOG2E : LOG2E;

  // ---- init: zero both A-staging buffers ----
  for (int i = tid; i < 2*MB*A1STR/2; i += NTHREADS) ((unsigned*)A1)[i] = 0u;
  for (int i = tid; i < 2*MB*A2STR/2; i += NTHREADS) ((unsigned*)A2)[i] = 0u;

  // ---- per-thread bias vectors for unit `un` (gate order i,f,g,o) ----
  floatx4 bi1v, bi2v;
  #pragma unroll
  for (int g = 0; g < 4; ++g) {
    float ws = (g == 2) ? 2.f * LOG2E : LOG2E;
    bi1v[g] = (bih0[g*64 + un] + bhh0[g*64 + un]) * ws;
    bi2v[g] = (bih1[g*64 + un] + bhh1[g*64 + un]) * ws;
  }

  // ---- stage x(0) into A1[0]; xcur = x(1) ----
  const int xb = tid / 7, xd = tid - xb * 7;
  const float* xbase = x + ((size_t)(b0 + (xb & 15)) * T_SEQ) * 7 + xd;
  float xcur = 0.f;
  if (tid < 112) {
    float xv = xbase[0];
    short xh = f2bf(xv); short xl = f2bf(xv - bf2f(xh));
    *(unsigned*)&A1[0][xb][128 + 2*xd] =
        (unsigned)(unsigned short)xh | ((unsigned)(unsigned short)xl << 16);
    xcur = xbase[7];
  }

  // ---- weight A-fragments in registers ----
  short8 B1f[5];
  short8 B2f[8];
  #pragma unroll
  for (int ks = 0; ks < 5; ++ks) {
    short8 f;
    #pragma unroll
    for (int jj = 0; jj < 8; ++jj) f[jj] = w1elem(ks*32 + quad8 + jj, n, wsc, Wih0, Whh0);
    B1f[ks] = f;
  }
  #pragma unroll
  for (int ks = 0; ks < 8; ++ks) {
    short8 f;
    #pragma unroll
    for (int jj = 0; jj < 8; ++jj) f[jj] = w2elem(ks*32 + quad8 + jj, n, wsc, Wih1, Whh1);
    B2f[ks] = f;
  }
  __syncthreads();

  float c1 = 0.f, c2 = 0.f;

#define STEP_X(NXT, XT)                                                      \
    if (tid < 112) {                                                         \
      short xh = f2bf(xcur); short xl = f2bf(xcur - bf2f(xh));               \
      *(unsigned*)&A1[NXT][xb][128 + 2*xd] =                                 \
          (unsigned)(unsigned short)xh | ((unsigned)(unsigned short)xl << 16);\
      xcur = xbase[7 * (XT)];                                                \
    }

#define STEP_FULL(CUR, NXT, IT)                                              \
  {                                                                          \
    int xt_ = (IT) + 2; if (xt_ > T_SEQ - 1) xt_ = T_SEQ - 1;                \
    STEP_X(NXT, xt_)                                                         \
    short8 hf0 = *(const short8*)&A1[CUR][l15][      quad8];                 \
    short8 hf1 = *(const short8*)&A1[CUR][l15][ 32 + quad8];                 \
    short8 hf2 = *(const short8*)&A1[CUR][l15][ 64 + quad8];                 \
    short8 hf3 = *(const short8*)&A1[CUR][l15][ 96 + quad8];                 \
    short8 hf4 = *(const short8*)&A1[CUR][l15][128 + quad8];                 \
    short8 h20 = *(const short8*)&A2[CUR][l15][      quad8];                 \
    short8 h21 = *(const short8*)&A2[CUR][l15][ 32 + quad8];                 \
    short8 h22 = *(const short8*)&A2[CUR][l15][ 64 + quad8];                 \
    short8 h23 = *(const short8*)&A2[CUR][l15][ 96 + quad8];                 \
    floatx4 p1 = bi1v;                                                       \
    p1 = MFMA(B1f[0], hf0, p1);                                              \
    p1 = MFMA(B1f[1], hf1, p1);                                              \
    p1 = MFMA(B1f[2], hf2, p1);                                              \
    p1 = MFMA(B1f[3], hf3, p1);                                              \
    p1 = MFMA(B1f[4], hf4, p1);                                              \
    floatx4 p2 = bi2v;                                                       \
    p2 = MFMA(B2f[0], hf0, p2);                                              \
    p2 = MFMA(B2f[1], hf1, p2);                                              \
    p2 = MFMA(B2f[2], hf2, p2);                                              \
    p2 = MFMA(B2f[3], hf3, p2);                                              \
    p2 = MFMA(B2f[4], h20, p2);                                              \
    p2 = MFMA(B2f[5], h21, p2);                                              \
    p2 = MFMA(B2f[6], h22, p2);                                              \
    p2 = MFMA(B2f[7], h23, p2);                                              \
    {                                                                        \
      float iv = sigm_p(p1[0]), fv = sigm_p(p1[1]);                          \
      float gv = tanh_p(p1[2]), ov = sigm_p(p1[3]);                          \
      c1 = fv * c1 + iv * gv;                                                \
      float h = ov * tanh_c(c1);                                             \
      short hh = f2bf(h); short hl = f2bf(h - bf2f(hh));                     \
      *(unsigned*)&A1[NXT][l15][2*un] =                                      \
          (unsigned)(unsigned short)hh | ((unsigned)(unsigned short)hl << 16);\
    }                                                                        \
    {                                                                        \
      float iv = sigm_p(p2[0]), fv = sigm_p(p2[1]);                          \
      float gv = tanh_p(p2[2]), ov = sigm_p(p2[3]);                          \
      c2 = fv * c2 + iv * gv;                                                \
      float h = ov * tanh_c(c2);                                             \
      short hh = f2bf(h); short hl = f2bf(h - bf2f(hh));                     \
      *(unsigned*)&A2[NXT][l15][2*un] =                                      \
          (unsigned)(unsigned short)hh | ((unsigned)(unsigned short)hl << 16);\
    }                                                                        \
    __syncthreads();                                                         \
  }

  // ---- it = 0 (prologue: GEMM1 + ew1 only; A2[1] keeps zeros = h2(-1)) ----
  {
    STEP_X(1, 2)
    short8 hf0 = *(const short8*)&A1[0][l15][      quad8];
    short8 hf1 = *(const short8*)&A1[0][l15][ 32 + quad8];
    short8 hf2 = *(const short8*)&A1[0][l15][ 64 + quad8];
    short8 hf3 = *(const short8*)&A1[0][l15][ 96 + quad8];
    short8 hf4 = *(const short8*)&A1[0][l15][128 + quad8];
    floatx4 p1 = bi1v;
    p1 = MFMA(B1f[0], hf0, p1);
    p1 = MFMA(B1f[1], hf1, p1);
    p1 = MFMA(B1f[2], hf2, p1);
    p1 = MFMA(B1f[3], hf3, p1);
    p1 = MFMA(B1f[4], hf4, p1);
    float iv = sigm_p(p1[0]), fv = sigm_p(p1[1]);
    float gv = tanh_p(p1[2]), ov = sigm_p(p1[3]);
    c1 = fv * c1 + iv * gv;
    float h = ov * tanh_c(c1);
    short hh = f2bf(h); short hl = f2bf(h - bf2f(hh));
    *(unsigned*)&A1[1][l15][2*un] =
        (unsigned)(unsigned short)hh | ((unsigned)(unsigned short)hl << 16);
    __syncthreads();
  }

  // ---- main: it = 1..510, two steps per trip ----
  #pragma unroll 1
  for (int k = 0; k < 255; ++k) {
    STEP_FULL(1, 0, 2*k + 1)
    STEP_FULL(0, 1, 2*k + 2)
  }
  // ---- it = 511 ----
  STEP_FULL(1, 0, 511)

  // ---- it = 512 (epilogue: GEMM2 + ew2 only, write h2 final) ----
  {
    short8 hf0 = *(const short8*)&A1[0][l15][      quad8];
    short8 hf1 = *(const short8*)&A1[0][l15][ 32 + quad8];
    short8 hf2 = *(const short8*)&A1[0][l15][ 64 + quad8];
    short8 hf3 = *(const short8*)&A1[0][l15][ 96 + quad8];
    short8 h20 = *(const short8*)&A2[0][l15][      quad8];
    short8 h21 = *(const short8*)&A2[0][l15][ 32 + quad8];
    short8 h22 = *(const short8*)&A2[0][l15][ 64 + quad8];
    short8 h23 = *(const short8*)&A2[0][l15][ 96 + quad8];
    floatx4 p2 = bi2v;
    p2 = MFMA(B2f[0], hf0, p2);
    p2 = MFMA(B2f[1], hf1, p2);
    p2 = MFMA(B2f[2], hf2, p2);
    p2 = MFMA(B2f[3], hf3, p2);
    p2 = MFMA(B2f[4], h20, p2);
    p2 = MFMA(B2f[5], h21, p2);
    p2 = MFMA(B2f[6], h22, p2);
    p2 = MFMA(B2f[7], h23, p2);
    float iv = sigm_p(p2[0]), fv = sigm_p(p2[1]);
    float gv = tanh_p(p2[2]), ov = sigm_p(p2[3]);
    c2 = fv * c2 + iv * gv;
    h2f[l15][un] = ov * tanh_c(c2);
    __syncthreads();
  }

  // ---- final FC ----
  if (tid < MB * 4) {
    int bbf = tid >> 2, o = tid & 3;
    float acc = bfc[o];
    #pragma unroll 8
    for (int kk = 0; kk < HID; ++kk) acc += h2f[bbf][kk] * Wfc[o*HID + kk];
    out[(size_t)(b0 + bbf) * 4 + o] = acc;
  }
}

extern "C" void kernel_launch(void* const* d_in, const int* in_sizes, int n_in,
                              void* d_out, int out_size, void* d_ws, size_t ws_size,
                              hipStream_t stream) {
  const float* x    = (const float*)d_in[0];
  const float* Wih0 = (const float*)d_in[1];
  const float* Whh0 = (const float*)d_in[2];
  const float* bih0 = (const float*)d_in[3];
  const float* bhh0 = (const float*)d_in[4];
  const float* Wih1 = (const float*)d_in[5];
  const float* Whh1 = (const float*)d_in[6];
  const float* bih1 = (const float*)d_in[7];
  const float* bhh1 = (const float*)d_in[8];
  const float* Wfc  = (const float*)d_in[9];
  const float* bfc  = (const float*)d_in[10];
  (void)d_ws; (void)ws_size; (void)n_in; (void)out_size;

  const int B = in_sizes[0] / (T_SEQ * 7);   // 4096
  dim3 grid(B / MB);
  lstm_fused<<<grid, NTHREADS, 0, stream>>>(x, Wih0, Whh0, bih0, bhh0,
                                            Wih1, Whh1, bih1, bhh1, Wfc, bfc,
                                            (float*)d_out);
}

// Round 9
// 471.455 us; speedup vs baseline: 1.9263x; 1.2973x over previous
//
#include <hip/hip_runtime.h>

#define T_SEQ 512
#define HID 64
#define MB 16             // batch rows per block
#define NTHREADS 1024     // 16 waves, 4/SIMD
// OPERAND-FLIPPED MFMA: A = weights (regs), B = h (LDS). D[gate-unit][batch]:
// lane (quad,l15) holds gates i,f,g,o (regs 0..3) of unit wave*4+quad, batch l15.
// PURE-bf16 h (h_lo dropped; h stored RNE — error budget measured R8 allows):
// A1 row: short u in [0,64) = h1[u]; [64,71) = x[d]; [71,96) zero.  K1=96, 3 ksteps
// A2 row: short u in [0,64) = h2[u].                                K2=128: 2+2 ksteps
#define A1STR 104   // shorts; 52 dw ≡ 20 mod 32 -> full bank spread, 2-way max
#define A2STR 72    // shorts; 36 dw ≡ 4 mod 32  -> full bank spread, 2-way max

typedef __attribute__((ext_vector_type(8))) short short8;
typedef __attribute__((ext_vector_type(4))) float floatx4;

#define LOG2E 1.4426950408889634f

__device__ __forceinline__ float bf2f(short b) {
  return __uint_as_float(((unsigned)(unsigned short)b) << 16);
}
__device__ __forceinline__ short f2bf_rne(float v) {
  unsigned u = __float_as_uint(v);
  return (short)((u + 0x7FFFu + ((u >> 16) & 1u)) >> 16);
}
__device__ __forceinline__ float rcp_(float x) { return __builtin_amdgcn_rcpf(x); }
// activations on PRE-SCALED gates: ap = LOG2E*a (i,f,o), yp = 2*LOG2E*y (g)
__device__ __forceinline__ float sigm_p(float ap) {
  return rcp_(1.f + __builtin_amdgcn_exp2f(-ap));
}
__device__ __forceinline__ float tanh_p(float yp) {
  return 1.f - 2.f * rcp_(__builtin_amdgcn_exp2f(yp) + 1.f);
}
__device__ __forceinline__ float tanh_c(float c) {         // unscaled c
  return tanh_p((2.f * LOG2E) * c);
}

// W1 slot k: k<64 -> Whh0[n][k]; 64..70 -> Wih0[n][k-64]; else 0.   (K1=96)
__device__ __forceinline__ short w1elem(int k, int n, float wsc,
                                        const float* __restrict__ Wih0,
                                        const float* __restrict__ Whh0) {
  float v;
  if      (k < 64) { v = Whh0[n*64 + k]; }
  else if (k < 71) { v = Wih0[n*7 + (k - 64)]; }
  else return (short)0;
  return f2bf_rne(v * wsc);
}
// W2 slot k: k<64 -> Wih1[n][k] (pairs h1); 64..127 -> Whh1[n][k-64] (pairs h2)
__device__ __forceinline__ short w2elem(int k, int n, float wsc,
                                        const float* __restrict__ Wih1,
                                        const float* __restrict__ Whh1) {
  float v;
  if (k < 64) { v = Wih1[n*64 + k]; }
  else        { v = Whh1[n*64 + (k - 64)]; }
  return f2bf_rne(v * wsc);
}

// A = weights (first arg), B = h (second arg)
#define MFMA(A, B, C) __builtin_amdgcn_mfma_f32_16x16x32_bf16((A), (B), (C), 0, 0, 0)

__global__ __launch_bounds__(NTHREADS, 4) void lstm_fused(
    const float* __restrict__ x,
    const float* __restrict__ Wih0, const float* __restrict__ Whh0,
    const float* __restrict__ bih0, const float* __restrict__ bhh0,
    const float* __restrict__ Wih1, const float* __restrict__ Whh1,
    const float* __restrict__ bih1, const float* __restrict__ bhh1,
    const float* __restrict__ Wfc,  const float* __restrict__ bfc,
    float* __restrict__ out)
{
  __shared__ __align__(16) short A1[2][MB][A1STR];
  __shared__ __align__(16) short A2[2][MB][A2STR];
  __shared__ float h2f[MB][HID + 4];

  const int tid  = threadIdx.x;
  const int lane = tid & 63;
  const int wave = tid >> 6;
  const int l15  = lane & 15;          // batch column (D n-index)
  const int quad = lane >> 4;
  const int quad8= quad * 8;
  const int g4   = l15 & 3;            // gate of this lane's A-frag rows
  const int b0   = blockIdx.x * MB;
  const int un   = wave * 4 + quad;    // unit owned post-MFMA
  const int n    = g4 * 64 + (wave * 4 + (l15 >> 2));  // A-frag weight row
  const float wsc = (g4 == 2) ? 2.f * LOG2E : LOG2E;

  // ---- init: zero both A-staging buffers ----
  for (int i = tid; i < 2*MB*A1STR/2; i += NTHREADS) ((unsigned*)A1)[i] = 0u;
  for (int i = tid; i < 2*MB*A2STR/2; i += NTHREADS) ((unsigned*)A2)[i] = 0u;

  // ---- per-thread bias vectors for unit `un` (gate order i,f,g,o) ----
  floatx4 bi1v, bi2v;
  #pragma unroll
  for (int g = 0; g < 4; ++g) {
    float ws = (g == 2) ? 2.f * LOG2E : LOG2E;
    bi1v[g] = (bih0[g*64 + un] + bhh0[g*64 + un]) * ws;
    bi2v[g] = (bih1[g*64 + un] + bhh1[g*64 + un]) * ws;
  }

  // ---- stage x(0) into A1[0]; xcur = x(1) ----
  const int xb = tid / 7, xd = tid - xb * 7;
  const float* xbase = x + ((size_t)(b0 + (xb & 15)) * T_SEQ) * 7 + xd;
  float xcur = 0.f;
  if (tid < 112) {
    A1[0][xb][64 + xd] = f2bf_rne(xbase[0]);
    xcur = xbase[7];
  }

  // ---- weight A-fragments in registers ----
  short8 B1f[3];
  short8 B2f[4];
  #pragma unroll
  for (int ks = 0; ks < 3; ++ks) {
    short8 f;
    #pragma unroll
    for (int jj = 0; jj < 8; ++jj) f[jj] = w1elem(ks*32 + quad8 + jj, n, wsc, Wih0, Whh0);
    B1f[ks] = f;
  }
  #pragma unroll
  for (int ks = 0; ks < 4; ++ks) {
    short8 f;
    #pragma unroll
    for (int jj = 0; jj < 8; ++jj) f[jj] = w2elem(ks*32 + quad8 + jj, n, wsc, Wih1, Whh1);
    B2f[ks] = f;
  }
  __syncthreads();

  float c1 = 0.f, c2 = 0.f;

#define STEP_X(NXT, XT)                                                      \
    if (tid < 112) {                                                         \
      A1[NXT][xb][64 + xd] = f2bf_rne(xcur);                                 \
      xcur = xbase[7 * (XT)];                                                \
    }

#define STEP_FULL(CUR, NXT, IT)                                              \
  {                                                                          \
    int xt_ = (IT) + 2; if (xt_ > T_SEQ - 1) xt_ = T_SEQ - 1;                \
    STEP_X(NXT, xt_)                                                         \
    short8 hf0 = *(const short8*)&A1[CUR][l15][      quad8];                 \
    short8 hf1 = *(const short8*)&A1[CUR][l15][ 32 + quad8];                 \
    short8 hfx = *(const short8*)&A1[CUR][l15][ 64 + quad8];                 \
    short8 h20 = *(const short8*)&A2[CUR][l15][      quad8];                 \
    short8 h21 = *(const short8*)&A2[CUR][l15][ 32 + quad8];                 \
    floatx4 p1 = bi1v;                                                       \
    p1 = MFMA(B1f[0], hf0, p1);                                              \
    p1 = MFMA(B1f[1], hf1, p1);                                              \
    p1 = MFMA(B1f[2], hfx, p1);                                              \
    floatx4 p2 = bi2v;                                                       \
    p2 = MFMA(B2f[0], hf0, p2);                                              \
    p2 = MFMA(B2f[1], hf1, p2);                                              \
    p2 = MFMA(B2f[2], h20, p2);                                              \
    p2 = MFMA(B2f[3], h21, p2);                                              \
    {                                                                        \
      float iv = sigm_p(p1[0]), fv = sigm_p(p1[1]);                          \
      float gv = tanh_p(p1[2]), ov = sigm_p(p1[3]);                          \
      c1 = fv * c1 + iv * gv;                                                \
      A1[NXT][l15][un] = f2bf_rne(ov * tanh_c(c1));                          \
    }                                                                        \
    {                                                                        \
      float iv = sigm_p(p2[0]), fv = sigm_p(p2[1]);                          \
      float gv = tanh_p(p2[2]), ov = sigm_p(p2[3]);                          \
      c2 = fv * c2 + iv * gv;                                                \
      A2[NXT][l15][un] = f2bf_rne(ov * tanh_c(c2));                          \
    }                                                                        \
    __syncthreads();                                                         \
  }

  // ---- it = 0 (prologue: GEMM1 + ew1 only; A2[1] keeps zeros = h2(-1)) ----
  {
    STEP_X(1, 2)
    short8 hf0 = *(const short8*)&A1[0][l15][      quad8];
    short8 hf1 = *(const short8*)&A1[0][l15][ 32 + quad8];
    short8 hfx = *(const short8*)&A1[0][l15][ 64 + quad8];
    floatx4 p1 = bi1v;
    p1 = MFMA(B1f[0], hf0, p1);
    p1 = MFMA(B1f[1], hf1, p1);
    p1 = MFMA(B1f[2], hfx, p1);
    float iv = sigm_p(p1[0]), fv = sigm_p(p1[1]);
    float gv = tanh_p(p1[2]), ov = sigm_p(p1[3]);
    c1 = fv * c1 + iv * gv;
    A1[1][l15][un] = f2bf_rne(ov * tanh_c(c1));
    __syncthreads();
  }

  // ---- main: it = 1..510, two steps per trip ----
  #pragma unroll 1
  for (int k = 0; k < 255; ++k) {
    STEP_FULL(1, 0, 2*k + 1)
    STEP_FULL(0, 1, 2*k + 2)
  }
  // ---- it = 511 ----
  STEP_FULL(1, 0, 511)

  // ---- it = 512 (epilogue: GEMM2 + ew2 only, write h2 final) ----
  {
    short8 hf0 = *(const short8*)&A1[0][l15][      quad8];
    short8 hf1 = *(const short8*)&A1[0][l15][ 32 + quad8];
    short8 h20 = *(const short8*)&A2[0][l15][      quad8];
    short8 h21 = *(const short8*)&A2[0][l15][ 32 + quad8];
    floatx4 p2 = bi2v;
    p2 = MFMA(B2f[0], hf0, p2);
    p2 = MFMA(B2f[1], hf1, p2);
    p2 = MFMA(B2f[2], h20, p2);
    p2 = MFMA(B2f[3], h21, p2);
    float iv = sigm_p(p2[0]), fv = sigm_p(p2[1]);
    float gv = tanh_p(p2[2]), ov = sigm_p(p2[3]);
    c2 = fv * c2 + iv * gv;
    h2f[l15][un] = ov * tanh_c(c2);
    __syncthreads();
  }

  // ---- final FC ----
  if (tid < MB * 4) {
    int bbf = tid >> 2, o = tid & 3;
    float acc = bfc[o];
    #pragma unroll 8
    for (int kk = 0; kk < HID; ++kk) acc += h2f[bbf][kk] * Wfc[o*HID + kk];
    out[(size_t)(b0 + bbf) * 4 + o] = acc;
  }
}

extern "C" void kernel_launch(void* const* d_in, const int* in_sizes, int n_in,
                              void* d_out, int out_size, void* d_ws, size_t ws_size,
                              hipStream_t stream) {
  const float* x    = (const float*)d_in[0];
  const float* Wih0 = (const float*)d_in[1];
  const float* Whh0 = (const float*)d_in[2];
  const float* bih0 = (const float*)d_in[3];
  const float* bhh0 = (const float*)d_in[4];
  const float* Wih1 = (const float*)d_in[5];
  const float* Whh1 = (const float*)d_in[6];
  const float* bih1 = (const float*)d_in[7];
  const float* bhh1 = (const float*)d_in[8];
  const float* Wfc  = (const float*)d_in[9];
  const float* bfc  = (const float*)d_in[10];
  (void)d_ws; (void)ws_size; (void)n_in; (void)out_size;

  const int B = in_sizes[0] / (T_SEQ * 7);   // 4096
  dim3 grid(B / MB);
  lstm_fused<<<grid, NTHREADS, 0, stream>>>(x, Wih0, Whh0, bih0, bhh0,
                                            Wih1, Whh1, bih1, bhh1, Wfc, bfc,
                                            (float*)d_out);
}

// Round 10
// 447.323 us; speedup vs baseline: 2.0303x; 1.0539x over previous
//
#include <hip/hip_runtime.h>

#define T_SEQ 512
#define HID 64
#define MB 16             // batch rows per block
#define NTHREADS 1024     // 16 waves: 0-7 layer1 (2 tiles), 8-15 layer2 (2 tiles)
// OPERAND-FLIPPED MFMA: A = weights (regs), B = h (LDS). D[gate-unit][batch].
// LAYER-SPLIT: L1 waves read {h1 x2, x} = 3 b128; L2 waves read {h1 x2, h2 x2} = 4.
// Both tiles of a wave share B-fragments -> 56 b128/CU-iter (was 80).
// UNIT PERMUTATION: LDS position p holds unit U(p) = (p&~7) + ((p&7)>>1) + ((p&1)<<2)
// so thread (wl,quad) owns units wl*8+quad, wl*8+4+quad at adjacent positions
// wl*8+2*quad, +1 -> single packed b32 h-store, 2-way max banks.
// A1 row: [0,64) h1 (permuted), [64,71) x (natural), [71,96) zero.  K1=96
// A2 row: [0,64) h2 (permuted).                                     K2=128
#define A1STR 104   // shorts (52 dw; 16B-aligned rows; reads/writes 2-way max)
#define A2STR 72    // shorts (36 dw)

typedef __attribute__((ext_vector_type(8))) short short8;
typedef __attribute__((ext_vector_type(4))) float floatx4;

#define LOG2E 1.4426950408889634f

__device__ __forceinline__ short f2bf_rne(float v) {
  unsigned u = __float_as_uint(v);
  return (short)((u + 0x7FFFu + ((u >> 16) & 1u)) >> 16);
}
__device__ __forceinline__ float rcp_(float x) { return __builtin_amdgcn_rcpf(x); }
__device__ __forceinline__ float sigm_p(float ap) {   // gates pre-scaled by LOG2E
  return rcp_(1.f + __builtin_amdgcn_exp2f(-ap));
}
__device__ __forceinline__ float tanh_p(float yp) {   // pre-scaled by 2*LOG2E
  return 1.f - 2.f * rcp_(__builtin_amdgcn_exp2f(yp) + 1.f);
}
__device__ __forceinline__ float tanh_c(float c) {
  return tanh_p((2.f * LOG2E) * c);
}

// unit stored at LDS h-position p
__device__ __forceinline__ int uofp(int p) {
  return (p & ~7) + ((p & 7) >> 1) + ((p & 1) << 2);
}

// Layer-1 weight at A-frag k-slot (K1=96): k<64 pairs h1 positions, 64..70 x
__device__ __forceinline__ short w1elem(int k, int n, float wsc,
                                        const float* __restrict__ Wih0,
                                        const float* __restrict__ Whh0) {
  float v;
  if      (k < 64) { v = Whh0[n*64 + uofp(k)]; }
  else if (k < 71) { v = Wih0[n*7 + (k - 64)]; }
  else return (short)0;
  return f2bf_rne(v * wsc);
}
// Layer-2 weight (K2=128): k<64 pairs h1 positions, 64..127 pairs h2 positions
__device__ __forceinline__ short w2elem(int k, int n, float wsc,
                                        const float* __restrict__ Wih1,
                                        const float* __restrict__ Whh1) {
  float v;
  if (k < 64) { v = Wih1[n*64 + uofp(k)]; }
  else        { v = Whh1[n*64 + uofp(k - 64)]; }
  return f2bf_rne(v * wsc);
}

// A = weights (first arg), B = h (second arg)
#define MFMA(A, B, C) __builtin_amdgcn_mfma_f32_16x16x32_bf16((A), (B), (C), 0, 0, 0)

#define PACK2(ha, hb)                                                        \
  ((unsigned)(unsigned short)f2bf_rne(ha) |                                  \
   ((unsigned)(unsigned short)f2bf_rne(hb) << 16))

__global__ __launch_bounds__(NTHREADS, 4) void lstm_fused(
    const float* __restrict__ x,
    const float* __restrict__ Wih0, const float* __restrict__ Whh0,
    const float* __restrict__ bih0, const float* __restrict__ bhh0,
    const float* __restrict__ Wih1, const float* __restrict__ Whh1,
    const float* __restrict__ bih1, const float* __restrict__ bhh1,
    const float* __restrict__ Wfc,  const float* __restrict__ bfc,
    float* __restrict__ out)
{
  __shared__ __align__(16) short A1[2][MB][A1STR];
  __shared__ __align__(16) short A2[2][MB][A2STR];
  __shared__ float h2f[MB][HID + 4];

  const int tid  = threadIdx.x;
  const int lane = tid & 63;
  const int wave = tid >> 6;           // 0..15
  const int wl   = wave & 7;           // index within layer group
  const bool isL1 = wave < 8;
  const int l15  = lane & 15;          // batch column
  const int quad = lane >> 4;
  const int quad8= quad * 8;
  const int g4   = l15 & 3;
  const int b0   = blockIdx.x * MB;
  const int u0   = wl*8 + quad;        // tile-0 owned unit
  const int u1   = u0 + 4;             // tile-1 owned unit
  const int hpos = wl*8 + 2*quad;      // packed h position (shorts, even)
  const int n0   = g4*64 + (wl*8 + (l15 >> 2));   // tile-0 weight row
  const int n1   = n0 + 4;                        // tile-1 weight row
  const float wsc = (g4 == 2) ? 2.f * LOG2E : LOG2E;

  // ---- zero both staging buffers (h(-1) = 0, x pad = 0) ----
  for (int i = tid; i < 2*MB*A1STR/2; i += NTHREADS) ((unsigned*)A1)[i] = 0u;
  for (int i = tid; i < 2*MB*A2STR/2; i += NTHREADS) ((unsigned*)A2)[i] = 0u;

  // ---- biases for owned units (this thread's layer) ----
  const float* bi_ = isL1 ? bih0 : bih1;
  const float* bh_ = isL1 ? bhh0 : bhh1;
  floatx4 bia, bib;
  #pragma unroll
  for (int g = 0; g < 4; ++g) {
    float ws = (g == 2) ? 2.f * LOG2E : LOG2E;
    bia[g] = (bi_[g*64 + u0] + bh_[g*64 + u0]) * ws;
    bib[g] = (bi_[g*64 + u1] + bh_[g*64 + u1]) * ws;
  }

  // ---- x staging: spread across all 8 L1 waves (2 batch rows each) ----
  const int xd   = lane & 31;
  const int xrow = 2*wl + (lane >> 5);
  const bool xact = isL1 && (xd < 7);
  const float* xbase = x + ((size_t)(b0 + xrow) * T_SEQ) * 7 + xd;
  float xcur = 0.f;
  if (xact) {
    A1[0][xrow][64 + xd] = f2bf_rne(xbase[0]);
    xcur = xbase[7];
  }

  // ---- weight A-fragments (per layer group; tiles a/b) ----
  short8 WA[4], WB[4];
  if (isL1) {
    #pragma unroll
    for (int ks = 0; ks < 3; ++ks) {
      short8 fa, fb;
      #pragma unroll
      for (int jj = 0; jj < 8; ++jj) {
        fa[jj] = w1elem(ks*32 + quad8 + jj, n0, wsc, Wih0, Whh0);
        fb[jj] = w1elem(ks*32 + quad8 + jj, n1, wsc, Wih0, Whh0);
      }
      WA[ks] = fa; WB[ks] = fb;
    }
  } else {
    #pragma unroll
    for (int ks = 0; ks < 4; ++ks) {
      short8 fa, fb;
      #pragma unroll
      for (int jj = 0; jj < 8; ++jj) {
        fa[jj] = w2elem(ks*32 + quad8 + jj, n0, wsc, Wih1, Whh1);
        fb[jj] = w2elem(ks*32 + quad8 + jj, n1, wsc, Wih1, Whh1);
      }
      WA[ks] = fa; WB[ks] = fb;
    }
  }
  __syncthreads();

  float ca = 0.f, cb = 0.f;   // c-state for owned (layer, unit) pair

#define STEP_X(NXT, XT)                                                      \
    if (xact) {                                                              \
      A1[NXT][xrow][64 + xd] = f2bf_rne(xcur);                               \
      xcur = xbase[7 * (XT)];                                                \
    }

#define EW2(PA, PB, HA, HB)                                                  \
    { float iv = sigm_p(PA[0]), fv = sigm_p(PA[1]);                          \
      float gv = tanh_p(PA[2]), ov = sigm_p(PA[3]);                          \
      ca = fv * ca + iv * gv;  HA = ov * tanh_c(ca); }                       \
    { float iv = sigm_p(PB[0]), fv = sigm_p(PB[1]);                          \
      float gv = tanh_p(PB[2]), ov = sigm_p(PB[3]);                          \
      cb = fv * cb + iv * gv;  HB = ov * tanh_c(cb); }

#define STEP_FULL(CUR, NXT, IT)                                              \
  {                                                                          \
    if (isL1) {                                                              \
      int xt_ = (IT) + 2; if (xt_ > T_SEQ - 1) xt_ = T_SEQ - 1;              \
      STEP_X(NXT, xt_)                                                       \
      short8 hf0 = *(const short8*)&A1[CUR][l15][     quad8];                \
      short8 hf1 = *(const short8*)&A1[CUR][l15][32 + quad8];                \
      short8 hfx = *(const short8*)&A1[CUR][l15][64 + quad8];                \
      floatx4 pa = bia, pb = bib;                                            \
      pa = MFMA(WA[0], hf0, pa);  pb = MFMA(WB[0], hf0, pb);                 \
      pa = MFMA(WA[1], hf1, pa);  pb = MFMA(WB[1], hf1, pb);                 \
      pa = MFMA(WA[2], hfx, pa);  pb = MFMA(WB[2], hfx, pb);                 \
      float ha, hb;                                                          \
      EW2(pa, pb, ha, hb)                                                    \
      *(unsigned*)&A1[NXT][l15][hpos] = PACK2(ha, hb);                       \
    } else {                                                                 \
      short8 hf0 = *(const short8*)&A1[CUR][l15][     quad8];                \
      short8 hf1 = *(const short8*)&A1[CUR][l15][32 + quad8];                \
      short8 h20 = *(const short8*)&A2[CUR][l15][     quad8];                \
      short8 h21 = *(const short8*)&A2[CUR][l15][32 + quad8];                \
      floatx4 pa = bia, pb = bib;                                            \
      pa = MFMA(WA[0], hf0, pa);  pb = MFMA(WB[0], hf0, pb);                 \
      pa = MFMA(WA[1], hf1, pa);  pb = MFMA(WB[1], hf1, pb);                 \
      pa = MFMA(WA[2], h20, pa);  pb = MFMA(WB[2], h20, pb);                 \
      pa = MFMA(WA[3], h21, pa);  pb = MFMA(WB[3], h21, pb);                 \
      float ha, hb;                                                          \
      EW2(pa, pb, ha, hb)                                                    \
      *(unsigned*)&A2[NXT][l15][hpos] = PACK2(ha, hb);                       \
    }                                                                        \
    __syncthreads();                                                         \
  }

  // ---- it = 0: L1 only (A2[1] keeps zeros = h2(-1)) ----
  {
    if (isL1) {
      STEP_X(1, 2)
      short8 hf0 = *(const short8*)&A1[0][l15][     quad8];
      short8 hf1 = *(const short8*)&A1[0][l15][32 + quad8];
      short8 hfx = *(const short8*)&A1[0][l15][64 + quad8];
      floatx4 pa = bia, pb = bib;
      pa = MFMA(WA[0], hf0, pa);  pb = MFMA(WB[0], hf0, pb);
      pa = MFMA(WA[1], hf1, pa);  pb = MFMA(WB[1], hf1, pb);
      pa = MFMA(WA[2], hfx, pa);  pb = MFMA(WB[2], hfx, pb);
      float ha, hb;
      EW2(pa, pb, ha, hb)
      *(unsigned*)&A1[1][l15][hpos] = PACK2(ha, hb);
    }
    __syncthreads();
  }

  // ---- main: it = 1..510, two steps per trip ----
  #pragma unroll 1
  for (int k = 0; k < 255; ++k) {
    STEP_FULL(1, 0, 2*k + 1)
    STEP_FULL(0, 1, 2*k + 2)
  }
  // ---- it = 511 ----
  STEP_FULL(1, 0, 511)

  // ---- it = 512: L2 only; write final h2 as f32 (natural unit index) ----
  {
    if (!isL1) {
      short8 hf0 = *(const short8*)&A1[0][l15][     quad8];
      short8 hf1 = *(const short8*)&A1[0][l15][32 + quad8];
      short8 h20 = *(const short8*)&A2[0][l15][     quad8];
      short8 h21 = *(const short8*)&A2[0][l15][32 + quad8];
      floatx4 pa = bia, pb = bib;
      pa = MFMA(WA[0], hf0, pa);  pb = MFMA(WB[0], hf0, pb);
      pa = MFMA(WA[1], hf1, pa);  pb = MFMA(WB[1], hf1, pb);
      pa = MFMA(WA[2], h20, pa);  pb = MFMA(WB[2], h20, pb);
      pa = MFMA(WA[3], h21, pa);  pb = MFMA(WB[3], h21, pb);
      float ha, hb;
      EW2(pa, pb, ha, hb)
      h2f[l15][u0] = ha;
      h2f[l15][u1] = hb;
    }
    __syncthreads();
  }

  // ---- final FC ----
  if (tid < MB * 4) {
    int bbf = tid >> 2, o = tid & 3;
    float acc = bfc[o];
    #pragma unroll 8
    for (int kk = 0; kk < HID; ++kk) acc += h2f[bbf][kk] * Wfc[o*HID + kk];
    out[(size_t)(b0 + bbf) * 4 + o] = acc;
  }
}

extern "C" void kernel_launch(void* const* d_in, const int* in_sizes, int n_in,
                              void* d_out, int out_size, void* d_ws, size_t ws_size,
                              hipStream_t stream) {
  const float* x    = (const float*)d_in[0];
  const float* Wih0 = (const float*)d_in[1];
  const float* Whh0 = (const float*)d_in[2];
  const float* bih0 = (const float*)d_in[3];
  const float* bhh0 = (const float*)d_in[4];
  const float* Wih1 = (const float*)d_in[5];
  const float* Whh1 = (const float*)d_in[6];
  const float* bih1 = (const float*)d_in[7];
  const float* bhh1 = (const float*)d_in[8];
  const float* Wfc  = (const float*)d_in[9];
  const float* bfc  = (const float*)d_in[10];
  (void)d_ws; (void)ws_size; (void)n_in; (void)out_size;

  const int B = in_sizes[0] / (T_SEQ * 7);   // 4096
  dim3 grid(B / MB);
  lstm_fused<<<grid, NTHREADS, 0, stream>>>(x, Wih0, Whh0, bih0, bhh0,
                                            Wih1, Whh1, bih1, bhh1, Wfc, bfc,
                                            (float*)d_out);
}